// Round 1
// baseline (66.522 us; speedup 1.0000x reference)
//
#include <hip/hip_runtime.h>

// MeanAggregator: out[i, :] = mean over e in [i*17, i*17+17) of feat[edge_dst[e], :]
// Shapes fixed by the reference: D = 128, DEG+1 = 17, B = E / 17.
//
// Layout: one block = 256 threads = 8 nodes x 32 lanes.
// Each lane owns one float4 chunk (16 B) of the 128-float row -> a gathered
// row is read as 32 lanes x 16 B = 512 B, fully coalesced.
// Edge indices are staged in LDS (read once per block, broadcast to lanes).

#define D_DIM 128
#define DEGP1 17
#define NODES_PER_BLOCK 8

__global__ __launch_bounds__(256) void mean_agg_kernel(
    const float* __restrict__ feat,      // [N_TOTAL, 128]
    const int*   __restrict__ edge_dst,  // [E]
    float*       __restrict__ out,       // [B, 128]
    int B)
{
    __shared__ int s_idx[NODES_PER_BLOCK * DEGP1];

    const int base_node = blockIdx.x * NODES_PER_BLOCK;

    // Cooperatively load this block's edge indices (8*17 = 136 ints).
    for (int t = threadIdx.x; t < NODES_PER_BLOCK * DEGP1; t += 256) {
        const int n = base_node + t / DEGP1;
        if (n < B) s_idx[t] = edge_dst[(size_t)n * DEGP1 + (t % DEGP1)];
    }
    __syncthreads();

    const int local_node = threadIdx.x >> 5;          // 0..7
    const int node = base_node + local_node;
    if (node >= B) return;

    const int lane4 = threadIdx.x & 31;               // float4 chunk 0..31
    const int col = lane4 * 4;                        // starting float column

    const int* idx = &s_idx[local_node * DEGP1];

    float4 acc = make_float4(0.f, 0.f, 0.f, 0.f);
    #pragma unroll
    for (int e = 0; e < DEGP1; ++e) {
        const int row = idx[e];                       // LDS broadcast per 32-lane group
        const float4 v = *reinterpret_cast<const float4*>(
            &feat[(size_t)row * D_DIM + col]);
        acc.x += v.x; acc.y += v.y; acc.z += v.z; acc.w += v.w;
    }

    const float inv = 1.0f / (float)DEGP1;
    float4 r = make_float4(acc.x * inv, acc.y * inv, acc.z * inv, acc.w * inv);
    *reinterpret_cast<float4*>(&out[(size_t)node * D_DIM + col]) = r;
}

extern "C" void kernel_launch(void* const* d_in, const int* in_sizes, int n_in,
                              void* d_out, int out_size, void* d_ws, size_t ws_size,
                              hipStream_t stream)
{
    const float* feat     = (const float*)d_in[0];  // features [N_TOTAL*128]
    // d_in[1] = edge_seg (unused: segments are contiguous fixed-size 17)
    const int*   edge_dst = (const int*)d_in[2];    // [E]
    // d_in[3] = num_nodes scalar on device; derive B from sizes instead.

    const int E = in_sizes[2];
    const int B = E / DEGP1;                        // 850000 / 17 = 50000

    float* out = (float*)d_out;

    const int grid = (B + NODES_PER_BLOCK - 1) / NODES_PER_BLOCK;
    mean_agg_kernel<<<grid, 256, 0, stream>>>(feat, edge_dst, out, B);
}